// Round 5
// baseline (265.987 us; speedup 1.0000x reference)
//
#include <hip/hip_runtime.h>
#include <hip/hip_bf16.h>

#define B_ 8
#define T_ 1024
#define C_ 1024
#define H_ 16
#define D_ 64
#define QKVLD 3072  // H_*3*D_

typedef short v8s __attribute__((ext_vector_type(8)));
typedef float v4f __attribute__((ext_vector_type(4)));
typedef float v16f __attribute__((ext_vector_type(16)));

__device__ __forceinline__ unsigned short f2b(float f) {
    unsigned int u = __builtin_bit_cast(unsigned int, f);
    unsigned int lsb = (u >> 16) & 1u;
    u += 0x7fffu + lsb;
    return (unsigned short)(u >> 16);
}

__device__ __forceinline__ float fexp2(float x) {
#if __has_builtin(__builtin_amdgcn_exp2f)
    return __builtin_amdgcn_exp2f(x);
#else
    return __expf(x * 0.69314718056f);
#endif
}

// async 16B global -> LDS. lds dest = wave-uniform base + lane*16.
#define GLOAD16(gp, lp)                                                          \
    __builtin_amdgcn_global_load_lds(                                            \
        (const __attribute__((address_space(1))) unsigned int*)(gp),             \
        (__attribute__((address_space(3))) unsigned int*)(lp), 16, 0, 0)

// ---------------- cast x (fp32 -> bf16), vectorized ----------------
__global__ void cast_x_kernel(const float* __restrict__ x, unsigned short* __restrict__ y, int n) {
    int i = (blockIdx.x * 256 + threadIdx.x) * 4;
    if (i < n) {
        float4 v = *(const float4*)(x + i);
        ushort4 o;
        o.x = f2b(v.x); o.y = f2b(v.y); o.z = f2b(v.z); o.w = f2b(v.w);
        *(ushort4*)(y + i) = o;
    }
}

// ---------------- Wq/Wk/Wv [H][C][D] -> WqkvT [3072][1024] bf16 ----------------
__global__ void transpose_wqkv(const float* __restrict__ Wq, const float* __restrict__ Wk,
                               const float* __restrict__ Wv, unsigned short* __restrict__ WqkvT) {
    int z = blockIdx.y;          // h*3 + part
    int h = z / 3, part = z % 3;
    const float* src = (part == 0 ? Wq : (part == 1 ? Wk : Wv)) + (size_t)h * C_ * D_;
    int c0 = blockIdx.x * 64;
    __shared__ unsigned short t[64][65];
    for (int i = threadIdx.x; i < 4096; i += 256) {
        int r = i >> 6, d = i & 63;
        t[d][r] = f2b(src[(size_t)(c0 + r) * D_ + d]);
    }
    __syncthreads();
    unsigned short* dst = WqkvT + (size_t)(h * 192 + part * 64) * C_;
    for (int i = threadIdx.x; i < 4096; i += 256) {
        int d = i >> 6, r = i & 63;
        dst[(size_t)d * C_ + c0 + r] = t[d][r];
    }
}

// ---------------- Wproj [1024][1024] -> WprojT [1024][1024] bf16 (B^T) ----------------
__global__ void transpose_wproj(const float* __restrict__ W, unsigned short* __restrict__ Wt) {
    int k0 = blockIdx.y * 64, n0 = blockIdx.x * 64;
    __shared__ unsigned short t[64][65];
    for (int i = threadIdx.x; i < 4096; i += 256) {
        int r = i >> 6, c = i & 63;
        t[c][r] = f2b(W[(size_t)(k0 + r) * C_ + n0 + c]);
    }
    __syncthreads();
    for (int i = threadIdx.x; i < 4096; i += 256) {
        int n = i >> 6, k = i & 63;
        Wt[(size_t)(n0 + n) * 1024 + k0 + k] = t[n][k];
    }
}

// ---------------- GEMM v3: 256x128 block tile, 32x32x16 MFMA, async dbuf pipeline ----------------
// 4 waves as 2(M)x2(N), wave tile 128x64 -> 44 FLOP/LDS-read-byte (1.4x the 64x64 structure).
// Double-buffered LDS staged via global_load_lds; prefetch issued a full iteration ahead of
// its vmcnt(0); one s_barrier per K-iteration (no drain-before-barrier stall).
// XOR swizzle: LDS slot (row, sc) holds global chunk sc ^ ((row>>1)&3)  (b128-floor conflicts).
template<int WRITE_MODE>
__global__ __launch_bounds__(256, 2) void gemm_bt(const unsigned short* __restrict__ A,
                                                  const unsigned short* __restrict__ Bt,
                                                  void* __restrict__ Cout,
                                                  const float* __restrict__ bias,
                                                  int M, int N, int K) {
    __shared__ unsigned short lA[2][256 * 32];   // 32 KB
    __shared__ unsigned short lB[2][128 * 32];   // 16 KB
    int tid = threadIdx.x;
    int m0 = blockIdx.y * 256, n0 = blockIdx.x * 128;
    int lane = tid & 63, w = tid >> 6;
    int half = lane >> 5, l32 = lane & 31;
    int wm = w >> 1, wn = w & 1;

    // DMA sources (XOR-swizzled within each row's 64B segment) + wave-uniform LDS offsets
    const unsigned short* gA[4];
    int offA[4];
    #pragma unroll
    for (int j = 0; j < 4; j++) {
        int c = j * 256 + tid;
        int row = c >> 2;
        int col8 = ((c & 3) ^ ((row >> 1) & 3)) * 8;
        gA[j] = A + (size_t)(m0 + row) * K + col8;
        offA[j] = (j * 256 + w * 64) * 16;
    }
    const unsigned short* gB[2];
    int offB[2];
    #pragma unroll
    for (int j = 0; j < 2; j++) {
        int c = j * 256 + tid;
        int row = c >> 2;
        int col8 = ((c & 3) ^ ((row >> 1) & 3)) * 8;
        gB[j] = Bt + (size_t)(n0 + row) * K + col8;
        offB[j] = (j * 256 + w * 64) * 16;
    }

    int am[4], bn[2];
    #pragma unroll
    for (int mi = 0; mi < 4; mi++) am[mi] = wm * 128 + mi * 32 + l32;
    #pragma unroll
    for (int ni = 0; ni < 2; ni++) bn[ni] = wn * 64 + ni * 32 + l32;

    v16f acc[4][2];
    #pragma unroll
    for (int mi = 0; mi < 4; mi++)
        #pragma unroll
        for (int ni = 0; ni < 2; ni++)
            #pragma unroll
            for (int r = 0; r < 16; r++) acc[mi][ni][r] = 0.f;

    int ktiles = K >> 5;
    // prologue: stage tile 0 -> buf 0
    #pragma unroll
    for (int j = 0; j < 4; j++) GLOAD16(gA[j], (char*)&lA[0][0] + offA[j]);
    #pragma unroll
    for (int j = 0; j < 2; j++) GLOAD16(gB[j], (char*)&lB[0][0] + offB[j]);

    for (int it = 0; it < ktiles; it++) {
        int cur = it & 1, nxt = cur ^ 1;
        // tile[it] (issued one iteration ago) has landed; everyone's reads of buf[nxt] are done
        __asm__ volatile("s_waitcnt vmcnt(0)" ::: "memory");
        __asm__ volatile("s_barrier" ::: "memory");
        // prefetch tile[it+1] -> buf[nxt]; stays in flight through this iteration's compute
        {
            int kn = (it + 1 < ktiles) ? (it + 1) * 32 : it * 32;   // clamp keeps vmcnt math fixed
            #pragma unroll
            for (int j = 0; j < 4; j++) GLOAD16(gA[j] + kn, (char*)&lA[nxt][0] + offA[j]);
            #pragma unroll
            for (int j = 0; j < 2; j++) GLOAD16(gB[j] + kn, (char*)&lB[nxt][0] + offB[j]);
        }
        // compute on buf[cur]: 2 k-steps of 16, 8 MFMA each
        #pragma unroll
        for (int step = 0; step < 2; step++) {
            int g = step * 2 + half;          // global 8-short chunk index within BK=32
            v8s af[4], bf[2];
            #pragma unroll
            for (int mi = 0; mi < 4; mi++)
                af[mi] = *(const v8s*)&lA[cur][am[mi] * 32 + ((g ^ ((am[mi] >> 1) & 3)) * 8)];
            #pragma unroll
            for (int ni = 0; ni < 2; ni++)
                bf[ni] = *(const v8s*)&lB[cur][bn[ni] * 32 + ((g ^ ((bn[ni] >> 1) & 3)) * 8)];
            #pragma unroll
            for (int mi = 0; mi < 4; mi++)
                #pragma unroll
                for (int ni = 0; ni < 2; ni++)
                    acc[mi][ni] = __builtin_amdgcn_mfma_f32_32x32x16_bf16(af[mi], bf[ni], acc[mi][ni], 0, 0, 0);
        }
    }
    // epilogue: C/D map col=lane&31, row=(reg&3)+8*(reg>>2)+4*(lane>>5)
    #pragma unroll
    for (int mi = 0; mi < 4; mi++) {
        #pragma unroll
        for (int ni = 0; ni < 2; ni++) {
            int col = n0 + wn * 64 + ni * 32 + l32;
            #pragma unroll
            for (int r = 0; r < 16; r++) {
                int row = m0 + wm * 128 + mi * 32 + (r & 3) + 8 * (r >> 2) + 4 * half;
                float v = acc[mi][ni][r];
                if (WRITE_MODE == 1)
                    ((float*)Cout)[(size_t)row * N + col] = v + bias[col];
                else
                    ((unsigned short*)Cout)[(size_t)row * N + col] = f2b(v);
            }
        }
    }
}

// ---------------- V [b,t,h,d] (inside QKV) -> Vt [b,h,d,t] ----------------
__global__ void transpose_v(const unsigned short* __restrict__ QKV, unsigned short* __restrict__ Vt) {
    int t0 = blockIdx.x * 64;
    int bh = blockIdx.y;
    int b = bh >> 4, h = bh & 15;
    __shared__ unsigned short t[64][65];
    for (int i = threadIdx.x; i < 4096; i += 256) {
        int r = i >> 6, d = i & 63;
        t[d][r] = QKV[(size_t)(b * T_ + t0 + r) * QKVLD + h * 192 + 128 + d];
    }
    __syncthreads();
    for (int i = threadIdx.x; i < 4096; i += 256) {
        int d = i >> 6, r = i & 63;
        Vt[((size_t)bh * 64 + d) * T_ + t0 + r] = t[d][r];
    }
}

// ---------------- Flash attention v4 (unchanged from R4) ----------------
__global__ __launch_bounds__(256) void attn_kernel(const unsigned short* __restrict__ QKV,
                                                   const unsigned short* __restrict__ Vt,
                                                   unsigned short* __restrict__ Ob) {
    int bh = blockIdx.x;                 // fast dim -> XCD = bh%8
    int qt = 7 - blockIdx.y;             // heavy-first
    int b = bh >> 4, h = bh & 15;
    int tid = threadIdx.x, lane = tid & 63, w = tid >> 6;
    int quad = lane >> 4, l16 = lane & 15;
    int qg0 = qt * 128 + w * 32;

    __shared__ unsigned short lK[2][2][64][32];  // [buf][d-half][s][32]  16 KB
    __shared__ unsigned short lV[2][64][32];     // [s-chunk][d][32]       8 KB
    __shared__ unsigned short lP[4][32][76];     // padded: conflict-free  19 KB

    v8s aq[2][2];
    #pragma unroll
    for (int st = 0; st < 2; st++) {
        const unsigned short* qp = QKV + (size_t)(b * T_ + qg0 + st * 16 + l16) * QKVLD + h * 192;
        aq[st][0] = *(const v8s*)(qp + quad * 8);
        aq[st][1] = *(const v8s*)(qp + 32 + quad * 8);
    }

    const unsigned short* gK[2];
    const unsigned short* gV[2];
    int ldsOff[2];
    #pragma unroll
    for (int j = 0; j < 2; j++) {
        int c = j * 256 + tid;
        int halfp = c >> 8, row = (c >> 2) & 63;
        int col8 = ((c & 3) ^ ((row >> 1) & 3)) * 8;
        gK[j] = QKV + (size_t)(b * T_ + row) * QKVLD + h * 192 + 64 + halfp * 32 + col8;
        gV[j] = Vt + ((size_t)bh * 64 + row) * T_ + halfp * 32 + col8;
        ldsOff[j] = (j * 256 + w * 64) * 16;
    }
    int rcol = (quad ^ ((l16 >> 1) & 3)) * 8;

    v4f accO[2][4];
    float lsum[2][4];
    #pragma unroll
    for (int st = 0; st < 2; st++)
        #pragma unroll
        for (int i = 0; i < 4; i++) { accO[st][i] = (v4f){0.f, 0.f, 0.f, 0.f}; lsum[st][i] = 0.f; }

    int ntiles = 2 * qt + 2;
    const float SC = 0.1803368801f;  // 0.125 * log2(e)

    #pragma unroll
    for (int j = 0; j < 2; j++)
        GLOAD16(gK[j], (char*)&lK[0][0][0][0] + ldsOff[j]);

    for (int it = 0; it < ntiles; it++) {
        int cur = it & 1, nxt = cur ^ 1;
        int s0 = it * 64;
        __asm__ volatile("s_waitcnt vmcnt(0)" ::: "memory");
        __asm__ volatile("s_barrier" ::: "memory");
        #pragma unroll
        for (int j = 0; j < 2; j++)
            GLOAD16(gV[j] + s0, (char*)&lV[0][0][0] + ldsOff[j]);
        __asm__ volatile("" ::: "memory");
        {
            int itn = (it + 1 < ntiles) ? it + 1 : it;
            size_t koff = (size_t)itn * 64 * QKVLD;
            #pragma unroll
            for (int j = 0; j < 2; j++)
                GLOAD16(gK[j] + koff, (char*)&lK[nxt][0][0][0] + ldsOff[j]);
        }
        bool act0 = (qg0 + 15 >= s0);
        bool act1 = (qg0 + 31 >= s0);
        if (act1) {
            v4f sf[2][4];
            #pragma unroll
            for (int nt = 0; nt < 4; nt++) {
                v8s bk0 = *(const v8s*)&lK[cur][0][nt * 16 + l16][rcol];
                v8s bk1 = *(const v8s*)&lK[cur][1][nt * 16 + l16][rcol];
                if (act0) {
                    v4f a = (v4f){0.f, 0.f, 0.f, 0.f};
                    a = __builtin_amdgcn_mfma_f32_16x16x32_bf16(aq[0][0], bk0, a, 0, 0, 0);
                    a = __builtin_amdgcn_mfma_f32_16x16x32_bf16(aq[0][1], bk1, a, 0, 0, 0);
                    sf[0][nt] = a;
                }
                v4f a1 = (v4f){0.f, 0.f, 0.f, 0.f};
                a1 = __builtin_amdgcn_mfma_f32_16x16x32_bf16(aq[1][0], bk0, a1, 0, 0, 0);
                a1 = __builtin_amdgcn_mfma_f32_16x16x32_bf16(aq[1][1], bk1, a1, 0, 0, 0);
                sf[1][nt] = a1;
            }
            bool diag = (it >= ntiles - 2);
            #pragma unroll
            for (int st = 0; st < 2; st++) {
                if (st == 0 && !act0) continue;
                if (diag) {
                    #pragma unroll
                    for (int nt = 0; nt < 4; nt++)
                        #pragma unroll
                        for (int r = 0; r < 4; r++) {
                            int sg = s0 + nt * 16 + l16;
                            int qg = qg0 + st * 16 + quad * 4 + r;
                            float p = (sg > qg) ? 0.f : fexp2(sf[st][nt][r] * SC);
                            lsum[st][r] += p;
                            lP[w][st * 16 + quad * 4 + r][nt * 16 + l16] = f2b(p);
                        }
                } else {
                    #pragma unroll
                    for (int nt = 0; nt < 4; nt++)
                        #pragma unroll
                        for (int r = 0; r < 4; r++) {
                            float p = fexp2(sf[st][nt][r] * SC);
                            lsum[st][r] += p;
                            lP[w][st * 16 + quad * 4 + r][nt * 16 + l16] = f2b(p);
                        }
                }
            }
        }
        __asm__ volatile("s_waitcnt vmcnt(2)" ::: "memory");
        __asm__ volatile("s_barrier" ::: "memory");
        __asm__ volatile("s_waitcnt lgkmcnt(0)" ::: "memory");
        if (act1) {
            #pragma unroll
            for (int sc = 0; sc < 2; sc++) {
                v8s ap0, ap1;
                if (act0) ap0 = *(const v8s*)&lP[w][l16][sc * 32 + quad * 8];
                ap1 = *(const v8s*)&lP[w][16 + l16][sc * 32 + quad * 8];
                #pragma unroll
                for (int dt = 0; dt < 4; dt++) {
                    v8s bv = *(const v8s*)&lV[sc][dt * 16 + l16][rcol];
                    if (act0) accO[0][dt] = __builtin_amdgcn_mfma_f32_16x16x32_bf16(ap0, bv, accO[0][dt], 0, 0, 0);
                    accO[1][dt] = __builtin_amdgcn_mfma_f32_16x16x32_bf16(ap1, bv, accO[1][dt], 0, 0, 0);
                }
            }
        }
    }
    #pragma unroll
    for (int st = 0; st < 2; st++)
        #pragma unroll
        for (int r = 0; r < 4; r++) {
            float s = lsum[st][r];
            #pragma unroll
            for (int off = 1; off < 16; off <<= 1) s += __shfl_xor(s, off, 64);
            float inv = 1.0f / s;
            int q = qg0 + st * 16 + quad * 4 + r;
            #pragma unroll
            for (int dt = 0; dt < 4; dt++) {
                int d = dt * 16 + l16;
                Ob[(size_t)(b * T_ + q) * (H_ * D_) + h * 64 + d] = f2b(accO[st][dt][r] * inv);
            }
        }
}

extern "C" void kernel_launch(void* const* d_in, const int* in_sizes, int n_in,
                              void* d_out, int out_size, void* d_ws, size_t ws_size,
                              hipStream_t stream) {
    const float* x     = (const float*)d_in[0];
    const float* Wq    = (const float*)d_in[1];
    const float* Wk    = (const float*)d_in[2];
    const float* Wv    = (const float*)d_in[3];
    const float* Wproj = (const float*)d_in[4];
    const float* bproj = (const float*)d_in[5];
    float* out = (float*)d_out;

    char* ws = (char*)d_ws;
    unsigned short* xb     = (unsigned short*)ws;                          // 16 MB  [8192][1024]
    unsigned short* WqkvT  = (unsigned short*)(ws + 16777216);             // 6 MB   [3072][1024]
    unsigned short* WprojT = (unsigned short*)(ws + 23068672);             // 2 MB   [1024][1024]
    unsigned short* QKV    = (unsigned short*)(ws + 25165824);             // 48 MB  [8192][3072]
    unsigned short* Vt     = (unsigned short*)(ws + 75497472);             // 16 MB  [B,H,D,T]
    unsigned short* Ob     = (unsigned short*)(ws + 92274688);             // 16 MB  [8192][1024]

    cast_x_kernel<<<dim3(8192), dim3(256), 0, stream>>>(x, xb, B_ * T_ * C_);
    transpose_wqkv<<<dim3(16, 48), dim3(256), 0, stream>>>(Wq, Wk, Wv, WqkvT);
    transpose_wproj<<<dim3(16, 16), dim3(256), 0, stream>>>(Wproj, WprojT);
    gemm_bt<0><<<dim3(24, 32), dim3(256), 0, stream>>>(xb, WqkvT, QKV, nullptr, 8192, 3072, 1024);
    transpose_v<<<dim3(16, 128), dim3(256), 0, stream>>>(QKV, Vt);
    attn_kernel<<<dim3(128, 8), dim3(256), 0, stream>>>(QKV, Vt, Ob);
    gemm_bt<1><<<dim3(8, 32), dim3(256), 0, stream>>>(Ob, WprojT, out, bproj, 8192, 1024, 1024);
}

// Round 6
// 262.317 us; speedup vs baseline: 1.0140x; 1.0140x over previous
//
#include <hip/hip_runtime.h>
#include <hip/hip_bf16.h>

#define B_ 8
#define T_ 1024
#define C_ 1024
#define H_ 16
#define D_ 64
#define QKVLD 3072  // H_*3*D_

typedef short v8s __attribute__((ext_vector_type(8)));
typedef float v4f __attribute__((ext_vector_type(4)));
typedef float v16f __attribute__((ext_vector_type(16)));

__device__ __forceinline__ unsigned short f2b(float f) {
    unsigned int u = __builtin_bit_cast(unsigned int, f);
    unsigned int lsb = (u >> 16) & 1u;
    u += 0x7fffu + lsb;
    return (unsigned short)(u >> 16);
}

__device__ __forceinline__ float fexp2(float x) {
#if __has_builtin(__builtin_amdgcn_exp2f)
    return __builtin_amdgcn_exp2f(x);
#else
    return __expf(x * 0.69314718056f);
#endif
}

// async 16B global -> LDS. lds dest = wave-uniform base + lane*16.
#define GLOAD16(gp, lp)                                                          \
    __builtin_amdgcn_global_load_lds(                                            \
        (const __attribute__((address_space(1))) unsigned int*)(gp),             \
        (__attribute__((address_space(3))) unsigned int*)(lp), 16, 0, 0)

// ---------------- cast x (fp32 -> bf16), vectorized ----------------
__global__ void cast_x_kernel(const float* __restrict__ x, unsigned short* __restrict__ y, int n) {
    int i = (blockIdx.x * 256 + threadIdx.x) * 4;
    if (i < n) {
        float4 v = *(const float4*)(x + i);
        ushort4 o;
        o.x = f2b(v.x); o.y = f2b(v.y); o.z = f2b(v.z); o.w = f2b(v.w);
        *(ushort4*)(y + i) = o;
    }
}

// ---------------- Wq/Wk/Wv [H][C][D] -> WqkvT [3072][1024] bf16 ----------------
__global__ void transpose_wqkv(const float* __restrict__ Wq, const float* __restrict__ Wk,
                               const float* __restrict__ Wv, unsigned short* __restrict__ WqkvT) {
    int z = blockIdx.y;          // h*3 + part
    int h = z / 3, part = z % 3;
    const float* src = (part == 0 ? Wq : (part == 1 ? Wk : Wv)) + (size_t)h * C_ * D_;
    int c0 = blockIdx.x * 64;
    __shared__ unsigned short t[64][65];
    for (int i = threadIdx.x; i < 4096; i += 256) {
        int r = i >> 6, d = i & 63;
        t[d][r] = f2b(src[(size_t)(c0 + r) * D_ + d]);
    }
    __syncthreads();
    unsigned short* dst = WqkvT + (size_t)(h * 192 + part * 64) * C_;
    for (int i = threadIdx.x; i < 4096; i += 256) {
        int d = i >> 6, r = i & 63;
        dst[(size_t)d * C_ + c0 + r] = t[d][r];
    }
}

// ---------------- Wproj [1024][1024] -> WprojT [1024][1024] bf16 (B^T) ----------------
__global__ void transpose_wproj(const float* __restrict__ W, unsigned short* __restrict__ Wt) {
    int k0 = blockIdx.y * 64, n0 = blockIdx.x * 64;
    __shared__ unsigned short t[64][65];
    for (int i = threadIdx.x; i < 4096; i += 256) {
        int r = i >> 6, c = i & 63;
        t[c][r] = f2b(W[(size_t)(k0 + r) * C_ + n0 + c]);
    }
    __syncthreads();
    for (int i = threadIdx.x; i < 4096; i += 256) {
        int n = i >> 6, k = i & 63;
        Wt[(size_t)(n0 + n) * 1024 + k0 + k] = t[n][k];
    }
}

// ---------------- GEMM v4: 3-stage async pipeline, 32x32x16 MFMA, XCD-stripe swizzle ----
// MB = A m-frags per wave (4 -> BM=256, 2 -> BM=128). BN=128. 4 waves as 2x2.
// 3 LDS buffers; iter i waits vmcnt(NL) (tile i landed, tile i+1 in flight), barriers,
// issues tile i+2 -> queue never drains (AITER pattern). XOR swizzle on staging columns.
template<int MB, int WRITE_MODE>
__global__ __launch_bounds__(256, (MB == 4) ? 2 : 3)
void gemm_bt(const unsigned short* __restrict__ A,
             const unsigned short* __restrict__ Bt,
             void* __restrict__ Cout,
             const float* __restrict__ bias,
             int M, int N, int K) {
    constexpr int BM = MB * 64;
    constexpr int ABUF = BM * 32;      // shorts per A buffer
    constexpr int BBUF = 128 * 32;
    __shared__ unsigned short lA[3 * ABUF];
    __shared__ unsigned short lB[3 * BBUF];

    int tid = threadIdx.x;
    int lane = tid & 63, w = tid >> 6;
    int half = lane >> 5, l32 = lane & 31;
    int wm = w >> 1, wn = w & 1;

    // XCD-stripe swizzle: xcd = g&7 (round-robin heuristic); each XCD owns an M-stripe.
    int g = blockIdx.x;
    int nbm = M / BM;
    int stripe = nbm >> 3;             // m-blocks per XCD
    int xcd = g & 7, s = g >> 3;
    int m0 = (xcd * stripe + (s % stripe)) * BM;
    int n0 = (s / stripe) * 128;

    const unsigned short* gA[MB];
    int offA[MB];
    #pragma unroll
    for (int j = 0; j < MB; j++) {
        int c = j * 256 + tid;
        int row = c >> 2;
        int col8 = ((c & 3) ^ ((row >> 1) & 3)) * 8;
        gA[j] = A + (size_t)(m0 + row) * K + col8;
        offA[j] = (j * 256 + w * 64) * 16;
    }
    const unsigned short* gB[2];
    int offB[2];
    #pragma unroll
    for (int j = 0; j < 2; j++) {
        int c = j * 256 + tid;
        int row = c >> 2;
        int col8 = ((c & 3) ^ ((row >> 1) & 3)) * 8;
        gB[j] = Bt + (size_t)(n0 + row) * K + col8;
        offB[j] = (j * 256 + w * 64) * 16;
    }

    int am[MB], bn[2];
    #pragma unroll
    for (int mi = 0; mi < MB; mi++) am[mi] = wm * (MB * 32) + mi * 32 + l32;
    #pragma unroll
    for (int ni = 0; ni < 2; ni++) bn[ni] = wn * 64 + ni * 32 + l32;

    v16f acc[MB][2];
    #pragma unroll
    for (int mi = 0; mi < MB; mi++)
        #pragma unroll
        for (int ni = 0; ni < 2; ni++)
            #pragma unroll
            for (int r = 0; r < 16; r++) acc[mi][ni][r] = 0.f;

    int kt = K >> 5;
    // prologue: T0 -> buf0, T1 -> buf1
    #pragma unroll
    for (int j = 0; j < MB; j++) GLOAD16(gA[j], (char*)lA + offA[j]);
    #pragma unroll
    for (int j = 0; j < 2; j++) GLOAD16(gB[j], (char*)lB + offB[j]);
    #pragma unroll
    for (int j = 0; j < MB; j++) GLOAD16(gA[j] + 32, (char*)(lA + ABUF) + offA[j]);
    #pragma unroll
    for (int j = 0; j < 2; j++) GLOAD16(gB[j] + 32, (char*)(lB + BBUF) + offB[j]);

    int cur = 0;
    for (int it = 0; it < kt; it++) {
        int nx2 = cur + 2; if (nx2 >= 3) nx2 -= 3;
        // tile[it] landed (NL = MB+2 loads of tile[it+1] may remain in flight)
        if constexpr (MB == 4) __asm__ volatile("s_waitcnt vmcnt(6)" ::: "memory");
        else                   __asm__ volatile("s_waitcnt vmcnt(4)" ::: "memory");
        __asm__ volatile("s_barrier" ::: "memory");
        // issue tile[it+2] -> buf[nx2] (clamped re-issue keeps vmcnt arithmetic fixed)
        {
            int kn = ((it + 2 < kt) ? it + 2 : kt - 1) << 5;
            #pragma unroll
            for (int j = 0; j < MB; j++) GLOAD16(gA[j] + kn, (char*)(lA + nx2 * ABUF) + offA[j]);
            #pragma unroll
            for (int j = 0; j < 2; j++) GLOAD16(gB[j] + kn, (char*)(lB + nx2 * BBUF) + offB[j]);
        }
        // compute on buf[cur]: 2 k-steps of 16
        const unsigned short* bufA = lA + cur * ABUF;
        const unsigned short* bufB = lB + cur * BBUF;
        #pragma unroll
        for (int step = 0; step < 2; step++) {
            int gch = step * 2 + half;
            v8s af[MB], bf[2];
            #pragma unroll
            for (int mi = 0; mi < MB; mi++)
                af[mi] = *(const v8s*)&bufA[am[mi] * 32 + ((gch ^ ((am[mi] >> 1) & 3)) * 8)];
            #pragma unroll
            for (int ni = 0; ni < 2; ni++)
                bf[ni] = *(const v8s*)&bufB[bn[ni] * 32 + ((gch ^ ((bn[ni] >> 1) & 3)) * 8)];
            #pragma unroll
            for (int mi = 0; mi < MB; mi++)
                #pragma unroll
                for (int ni = 0; ni < 2; ni++)
                    acc[mi][ni] = __builtin_amdgcn_mfma_f32_32x32x16_bf16(af[mi], bf[ni], acc[mi][ni], 0, 0, 0);
        }
        cur = cur + 1; if (cur >= 3) cur -= 3;
    }
    // epilogue: C/D map col=lane&31, row=(reg&3)+8*(reg>>2)+4*(lane>>5)
    #pragma unroll
    for (int mi = 0; mi < MB; mi++) {
        #pragma unroll
        for (int ni = 0; ni < 2; ni++) {
            int col = n0 + wn * 64 + ni * 32 + l32;
            #pragma unroll
            for (int r = 0; r < 16; r++) {
                int row = m0 + wm * (MB * 32) + mi * 32 + (r & 3) + 8 * (r >> 2) + 4 * half;
                float v = acc[mi][ni][r];
                if (WRITE_MODE == 1)
                    ((float*)Cout)[(size_t)row * N + col] = v + bias[col];
                else
                    ((unsigned short*)Cout)[(size_t)row * N + col] = f2b(v);
            }
        }
    }
}

// ---------------- V [b,t,h,d] (inside QKV) -> Vt [b,h,d,t] ----------------
__global__ void transpose_v(const unsigned short* __restrict__ QKV, unsigned short* __restrict__ Vt) {
    int t0 = blockIdx.x * 64;
    int bh = blockIdx.y;
    int b = bh >> 4, h = bh & 15;
    __shared__ unsigned short t[64][65];
    for (int i = threadIdx.x; i < 4096; i += 256) {
        int r = i >> 6, d = i & 63;
        t[d][r] = QKV[(size_t)(b * T_ + t0 + r) * QKVLD + h * 192 + 128 + d];
    }
    __syncthreads();
    for (int i = threadIdx.x; i < 4096; i += 256) {
        int d = i >> 6, r = i & 63;
        Vt[((size_t)bh * 64 + d) * T_ + t0 + r] = t[d][r];
    }
}

// ---------------- Flash attention v4 (unchanged) ----------------
__global__ __launch_bounds__(256) void attn_kernel(const unsigned short* __restrict__ QKV,
                                                   const unsigned short* __restrict__ Vt,
                                                   unsigned short* __restrict__ Ob) {
    int bh = blockIdx.x;                 // fast dim -> XCD = bh%8
    int qt = 7 - blockIdx.y;             // heavy-first
    int b = bh >> 4, h = bh & 15;
    int tid = threadIdx.x, lane = tid & 63, w = tid >> 6;
    int quad = lane >> 4, l16 = lane & 15;
    int qg0 = qt * 128 + w * 32;

    __shared__ unsigned short lK[2][2][64][32];  // [buf][d-half][s][32]  16 KB
    __shared__ unsigned short lV[2][64][32];     // [s-chunk][d][32]       8 KB
    __shared__ unsigned short lP[4][32][76];     // padded: conflict-free  19 KB

    v8s aq[2][2];
    #pragma unroll
    for (int st = 0; st < 2; st++) {
        const unsigned short* qp = QKV + (size_t)(b * T_ + qg0 + st * 16 + l16) * QKVLD + h * 192;
        aq[st][0] = *(const v8s*)(qp + quad * 8);
        aq[st][1] = *(const v8s*)(qp + 32 + quad * 8);
    }

    const unsigned short* gK[2];
    const unsigned short* gV[2];
    int ldsOff[2];
    #pragma unroll
    for (int j = 0; j < 2; j++) {
        int c = j * 256 + tid;
        int halfp = c >> 8, row = (c >> 2) & 63;
        int col8 = ((c & 3) ^ ((row >> 1) & 3)) * 8;
        gK[j] = QKV + (size_t)(b * T_ + row) * QKVLD + h * 192 + 64 + halfp * 32 + col8;
        gV[j] = Vt + ((size_t)bh * 64 + row) * T_ + halfp * 32 + col8;
        ldsOff[j] = (j * 256 + w * 64) * 16;
    }
    int rcol = (quad ^ ((l16 >> 1) & 3)) * 8;

    v4f accO[2][4];
    float lsum[2][4];
    #pragma unroll
    for (int st = 0; st < 2; st++)
        #pragma unroll
        for (int i = 0; i < 4; i++) { accO[st][i] = (v4f){0.f, 0.f, 0.f, 0.f}; lsum[st][i] = 0.f; }

    int ntiles = 2 * qt + 2;
    const float SC = 0.1803368801f;  // 0.125 * log2(e)

    #pragma unroll
    for (int j = 0; j < 2; j++)
        GLOAD16(gK[j], (char*)&lK[0][0][0][0] + ldsOff[j]);

    for (int it = 0; it < ntiles; it++) {
        int cur = it & 1, nxt = cur ^ 1;
        int s0 = it * 64;
        __asm__ volatile("s_waitcnt vmcnt(0)" ::: "memory");
        __asm__ volatile("s_barrier" ::: "memory");
        #pragma unroll
        for (int j = 0; j < 2; j++)
            GLOAD16(gV[j] + s0, (char*)&lV[0][0][0] + ldsOff[j]);
        __asm__ volatile("" ::: "memory");
        {
            int itn = (it + 1 < ntiles) ? it + 1 : it;
            size_t koff = (size_t)itn * 64 * QKVLD;
            #pragma unroll
            for (int j = 0; j < 2; j++)
                GLOAD16(gK[j] + koff, (char*)&lK[nxt][0][0][0] + ldsOff[j]);
        }
        bool act0 = (qg0 + 15 >= s0);
        bool act1 = (qg0 + 31 >= s0);
        if (act1) {
            v4f sf[2][4];
            #pragma unroll
            for (int nt = 0; nt < 4; nt++) {
                v8s bk0 = *(const v8s*)&lK[cur][0][nt * 16 + l16][rcol];
                v8s bk1 = *(const v8s*)&lK[cur][1][nt * 16 + l16][rcol];
                if (act0) {
                    v4f a = (v4f){0.f, 0.f, 0.f, 0.f};
                    a = __builtin_amdgcn_mfma_f32_16x16x32_bf16(aq[0][0], bk0, a, 0, 0, 0);
                    a = __builtin_amdgcn_mfma_f32_16x16x32_bf16(aq[0][1], bk1, a, 0, 0, 0);
                    sf[0][nt] = a;
                }
                v4f a1 = (v4f){0.f, 0.f, 0.f, 0.f};
                a1 = __builtin_amdgcn_mfma_f32_16x16x32_bf16(aq[1][0], bk0, a1, 0, 0, 0);
                a1 = __builtin_amdgcn_mfma_f32_16x16x32_bf16(aq[1][1], bk1, a1, 0, 0, 0);
                sf[1][nt] = a1;
            }
            bool diag = (it >= ntiles - 2);
            #pragma unroll
            for (int st = 0; st < 2; st++) {
                if (st == 0 && !act0) continue;
                if (diag) {
                    #pragma unroll
                    for (int nt = 0; nt < 4; nt++)
                        #pragma unroll
                        for (int r = 0; r < 4; r++) {
                            int sg = s0 + nt * 16 + l16;
                            int qg = qg0 + st * 16 + quad * 4 + r;
                            float p = (sg > qg) ? 0.f : fexp2(sf[st][nt][r] * SC);
                            lsum[st][r] += p;
                            lP[w][st * 16 + quad * 4 + r][nt * 16 + l16] = f2b(p);
                        }
                } else {
                    #pragma unroll
                    for (int nt = 0; nt < 4; nt++)
                        #pragma unroll
                        for (int r = 0; r < 4; r++) {
                            float p = fexp2(sf[st][nt][r] * SC);
                            lsum[st][r] += p;
                            lP[w][st * 16 + quad * 4 + r][nt * 16 + l16] = f2b(p);
                        }
                }
            }
        }
        __asm__ volatile("s_waitcnt vmcnt(2)" ::: "memory");
        __asm__ volatile("s_barrier" ::: "memory");
        __asm__ volatile("s_waitcnt lgkmcnt(0)" ::: "memory");
        if (act1) {
            #pragma unroll
            for (int sc = 0; sc < 2; sc++) {
                v8s ap0, ap1;
                if (act0) ap0 = *(const v8s*)&lP[w][l16][sc * 32 + quad * 8];
                ap1 = *(const v8s*)&lP[w][16 + l16][sc * 32 + quad * 8];
                #pragma unroll
                for (int dt = 0; dt < 4; dt++) {
                    v8s bv = *(const v8s*)&lV[sc][dt * 16 + l16][rcol];
                    if (act0) accO[0][dt] = __builtin_amdgcn_mfma_f32_16x16x32_bf16(ap0, bv, accO[0][dt], 0, 0, 0);
                    accO[1][dt] = __builtin_amdgcn_mfma_f32_16x16x32_bf16(ap1, bv, accO[1][dt], 0, 0, 0);
                }
            }
        }
    }
    #pragma unroll
    for (int st = 0; st < 2; st++)
        #pragma unroll
        for (int r = 0; r < 4; r++) {
            float s = lsum[st][r];
            #pragma unroll
            for (int off = 1; off < 16; off <<= 1) s += __shfl_xor(s, off, 64);
            float inv = 1.0f / s;
            int q = qg0 + st * 16 + quad * 4 + r;
            #pragma unroll
            for (int dt = 0; dt < 4; dt++) {
                int d = dt * 16 + l16;
                Ob[(size_t)(b * T_ + q) * (H_ * D_) + h * 64 + d] = f2b(accO[st][dt][r] * inv);
            }
        }
}

extern "C" void kernel_launch(void* const* d_in, const int* in_sizes, int n_in,
                              void* d_out, int out_size, void* d_ws, size_t ws_size,
                              hipStream_t stream) {
    const float* x     = (const float*)d_in[0];
    const float* Wq    = (const float*)d_in[1];
    const float* Wk    = (const float*)d_in[2];
    const float* Wv    = (const float*)d_in[3];
    const float* Wproj = (const float*)d_in[4];
    const float* bproj = (const float*)d_in[5];
    float* out = (float*)d_out;

    char* ws = (char*)d_ws;
    unsigned short* xb     = (unsigned short*)ws;                          // 16 MB  [8192][1024]
    unsigned short* WqkvT  = (unsigned short*)(ws + 16777216);             // 6 MB   [3072][1024]
    unsigned short* WprojT = (unsigned short*)(ws + 23068672);             // 2 MB   [1024][1024]
    unsigned short* QKV    = (unsigned short*)(ws + 25165824);             // 48 MB  [8192][3072]
    unsigned short* Vt     = (unsigned short*)(ws + 75497472);             // 16 MB  [B,H,D,T]
    unsigned short* Ob     = (unsigned short*)(ws + 92274688);             // 16 MB  [8192][1024]

    cast_x_kernel<<<dim3(8192), dim3(256), 0, stream>>>(x, xb, B_ * T_ * C_);
    transpose_wqkv<<<dim3(16, 48), dim3(256), 0, stream>>>(Wq, Wk, Wv, WqkvT);
    transpose_wproj<<<dim3(16, 16), dim3(256), 0, stream>>>(Wproj, WprojT);
    // QKV: M=8192 (32 m-blocks of 256), N=3072 (24 n-blocks) -> 768 blocks
    gemm_bt<4, 0><<<dim3(768), dim3(256), 0, stream>>>(xb, WqkvT, QKV, nullptr, 8192, 3072, 1024);
    transpose_v<<<dim3(16, 128), dim3(256), 0, stream>>>(QKV, Vt);
    attn_kernel<<<dim3(128, 8), dim3(256), 0, stream>>>(QKV, Vt, Ob);
    // proj: M=8192 (64 m-blocks of 128), N=1024 (8 n-blocks) -> 512 blocks
    gemm_bt<2, 1><<<dim3(512), dim3(256), 0, stream>>>(Ob, WprojT, out, bproj, 8192, 1024, 1024);
}

// Round 7
// 241.859 us; speedup vs baseline: 1.0998x; 1.0846x over previous
//
#include <hip/hip_runtime.h>
#include <hip/hip_bf16.h>

#define B_ 8
#define T_ 1024
#define C_ 1024
#define H_ 16
#define D_ 64
#define QKVLD 3072  // H_*3*D_

typedef short v8s __attribute__((ext_vector_type(8)));
typedef float v4f __attribute__((ext_vector_type(4)));
typedef float v16f __attribute__((ext_vector_type(16)));

__device__ __forceinline__ unsigned short f2b(float f) {
    unsigned int u = __builtin_bit_cast(unsigned int, f);
    unsigned int lsb = (u >> 16) & 1u;
    u += 0x7fffu + lsb;
    return (unsigned short)(u >> 16);
}

__device__ __forceinline__ float fexp2(float x) {
#if __has_builtin(__builtin_amdgcn_exp2f)
    return __builtin_amdgcn_exp2f(x);
#else
    return __expf(x * 0.69314718056f);
#endif
}

// async 16B global -> LDS. lds dest = wave-uniform base + lane*16.
#define GLOAD16(gp, lp)                                                          \
    __builtin_amdgcn_global_load_lds(                                            \
        (const __attribute__((address_space(1))) unsigned int*)(gp),             \
        (__attribute__((address_space(3))) unsigned int*)(lp), 16, 0, 0)

// ---------------- cast x (fp32 -> bf16), vectorized ----------------
__global__ void cast_x_kernel(const float* __restrict__ x, unsigned short* __restrict__ y, int n) {
    int i = (blockIdx.x * 256 + threadIdx.x) * 4;
    if (i < n) {
        float4 v = *(const float4*)(x + i);
        ushort4 o;
        o.x = f2b(v.x); o.y = f2b(v.y); o.z = f2b(v.z); o.w = f2b(v.w);
        *(ushort4*)(y + i) = o;
    }
}

// ---------------- Wq/Wk/Wv [H][C][D] -> WqkvT [3072][1024] bf16 ----------------
__global__ void transpose_wqkv(const float* __restrict__ Wq, const float* __restrict__ Wk,
                               const float* __restrict__ Wv, unsigned short* __restrict__ WqkvT) {
    int z = blockIdx.y;          // h*3 + part
    int h = z / 3, part = z % 3;
    const float* src = (part == 0 ? Wq : (part == 1 ? Wk : Wv)) + (size_t)h * C_ * D_;
    int c0 = blockIdx.x * 64;
    __shared__ unsigned short t[64][65];
    for (int i = threadIdx.x; i < 4096; i += 256) {
        int r = i >> 6, d = i & 63;
        t[d][r] = f2b(src[(size_t)(c0 + r) * D_ + d]);
    }
    __syncthreads();
    unsigned short* dst = WqkvT + (size_t)(h * 192 + part * 64) * C_;
    for (int i = threadIdx.x; i < 4096; i += 256) {
        int d = i >> 6, r = i & 63;
        dst[(size_t)d * C_ + c0 + r] = t[d][r];
    }
}

// ---------------- Wproj [1024][1024] -> WprojT [1024][1024] bf16 (B^T) ----------------
__global__ void transpose_wproj(const float* __restrict__ W, unsigned short* __restrict__ Wt) {
    int k0 = blockIdx.y * 64, n0 = blockIdx.x * 64;
    __shared__ unsigned short t[64][65];
    for (int i = threadIdx.x; i < 4096; i += 256) {
        int r = i >> 6, c = i & 63;
        t[c][r] = f2b(W[(size_t)(k0 + r) * C_ + n0 + c]);
    }
    __syncthreads();
    for (int i = threadIdx.x; i < 4096; i += 256) {
        int n = i >> 6, k = i & 63;
        Wt[(size_t)(n0 + n) * 1024 + k0 + k] = t[n][k];
    }
}

// ---------------- GEMM v2s (R5-exact): 256x128 tile, 32x32x16 MFMA, 2-stage dbuf ----------
// 4 waves as 2(M)x2(N), wave tile 128x64. One s_barrier per K-iter; prefetch issued a full
// iteration before its vmcnt(0). XOR swizzle on staging columns (conflict-free b128 floor).
__global__ __launch_bounds__(256, 2) void gemm_qkv(const unsigned short* __restrict__ A,
                                                   const unsigned short* __restrict__ Bt,
                                                   unsigned short* __restrict__ Cout,
                                                   int M, int N, int K) {
    __shared__ unsigned short lA[2][256 * 32];   // 32 KB
    __shared__ unsigned short lB[2][128 * 32];   // 16 KB
    int tid = threadIdx.x;
    int m0 = blockIdx.y * 256, n0 = blockIdx.x * 128;
    int lane = tid & 63, w = tid >> 6;
    int half = lane >> 5, l32 = lane & 31;
    int wm = w >> 1, wn = w & 1;

    const unsigned short* gA[4];
    int offA[4];
    #pragma unroll
    for (int j = 0; j < 4; j++) {
        int c = j * 256 + tid;
        int row = c >> 2;
        int col8 = ((c & 3) ^ ((row >> 1) & 3)) * 8;
        gA[j] = A + (size_t)(m0 + row) * K + col8;
        offA[j] = (j * 256 + w * 64) * 16;
    }
    const unsigned short* gB[2];
    int offB[2];
    #pragma unroll
    for (int j = 0; j < 2; j++) {
        int c = j * 256 + tid;
        int row = c >> 2;
        int col8 = ((c & 3) ^ ((row >> 1) & 3)) * 8;
        gB[j] = Bt + (size_t)(n0 + row) * K + col8;
        offB[j] = (j * 256 + w * 64) * 16;
    }

    int am[4], bn[2];
    #pragma unroll
    for (int mi = 0; mi < 4; mi++) am[mi] = wm * 128 + mi * 32 + l32;
    #pragma unroll
    for (int ni = 0; ni < 2; ni++) bn[ni] = wn * 64 + ni * 32 + l32;

    v16f acc[4][2];
    #pragma unroll
    for (int mi = 0; mi < 4; mi++)
        #pragma unroll
        for (int ni = 0; ni < 2; ni++)
            #pragma unroll
            for (int r = 0; r < 16; r++) acc[mi][ni][r] = 0.f;

    int ktiles = K >> 5;
    #pragma unroll
    for (int j = 0; j < 4; j++) GLOAD16(gA[j], (char*)&lA[0][0] + offA[j]);
    #pragma unroll
    for (int j = 0; j < 2; j++) GLOAD16(gB[j], (char*)&lB[0][0] + offB[j]);

    for (int it = 0; it < ktiles; it++) {
        int cur = it & 1, nxt = cur ^ 1;
        __asm__ volatile("s_waitcnt vmcnt(0)" ::: "memory");
        __asm__ volatile("s_barrier" ::: "memory");
        {
            int kn = (it + 1 < ktiles) ? (it + 1) * 32 : it * 32;
            #pragma unroll
            for (int j = 0; j < 4; j++) GLOAD16(gA[j] + kn, (char*)&lA[nxt][0] + offA[j]);
            #pragma unroll
            for (int j = 0; j < 2; j++) GLOAD16(gB[j] + kn, (char*)&lB[nxt][0] + offB[j]);
        }
        #pragma unroll
        for (int step = 0; step < 2; step++) {
            int g = step * 2 + half;
            v8s af[4], bf[2];
            #pragma unroll
            for (int mi = 0; mi < 4; mi++)
                af[mi] = *(const v8s*)&lA[cur][am[mi] * 32 + ((g ^ ((am[mi] >> 1) & 3)) * 8)];
            #pragma unroll
            for (int ni = 0; ni < 2; ni++)
                bf[ni] = *(const v8s*)&lB[cur][bn[ni] * 32 + ((g ^ ((bn[ni] >> 1) & 3)) * 8)];
            #pragma unroll
            for (int mi = 0; mi < 4; mi++)
                #pragma unroll
                for (int ni = 0; ni < 2; ni++)
                    acc[mi][ni] = __builtin_amdgcn_mfma_f32_32x32x16_bf16(af[mi], bf[ni], acc[mi][ni], 0, 0, 0);
        }
    }
    #pragma unroll
    for (int mi = 0; mi < 4; mi++) {
        #pragma unroll
        for (int ni = 0; ni < 2; ni++) {
            int col = n0 + wn * 64 + ni * 32 + l32;
            #pragma unroll
            for (int r = 0; r < 16; r++) {
                int row = m0 + wm * 128 + mi * 32 + (r & 3) + 8 * (r >> 2) + 4 * half;
                Cout[(size_t)row * N + col] = f2b(acc[mi][ni][r]);
            }
        }
    }
}

// ---------------- GEMM v3s (R6-exact, MB=2): 128x128, 3-stage pipeline, XCD stripe ------
__global__ __launch_bounds__(256, 3) void gemm_proj(const unsigned short* __restrict__ A,
                                                    const unsigned short* __restrict__ Bt,
                                                    float* __restrict__ Cout,
                                                    const float* __restrict__ bias,
                                                    int M, int N, int K) {
    constexpr int ABUF = 128 * 32;
    constexpr int BBUF = 128 * 32;
    __shared__ unsigned short lA[3 * ABUF];
    __shared__ unsigned short lB[3 * BBUF];

    int tid = threadIdx.x;
    int lane = tid & 63, w = tid >> 6;
    int half = lane >> 5, l32 = lane & 31;
    int wm = w >> 1, wn = w & 1;

    int g = blockIdx.x;
    int nbm = M / 128;
    int stripe = nbm >> 3;
    int xcd = g & 7, s = g >> 3;
    int m0 = (xcd * stripe + (s % stripe)) * 128;
    int n0 = (s / stripe) * 128;

    const unsigned short* gA[2];
    int offA[2];
    #pragma unroll
    for (int j = 0; j < 2; j++) {
        int c = j * 256 + tid;
        int row = c >> 2;
        int col8 = ((c & 3) ^ ((row >> 1) & 3)) * 8;
        gA[j] = A + (size_t)(m0 + row) * K + col8;
        offA[j] = (j * 256 + w * 64) * 16;
    }
    const unsigned short* gB[2];
    int offB[2];
    #pragma unroll
    for (int j = 0; j < 2; j++) {
        int c = j * 256 + tid;
        int row = c >> 2;
        int col8 = ((c & 3) ^ ((row >> 1) & 3)) * 8;
        gB[j] = Bt + (size_t)(n0 + row) * K + col8;
        offB[j] = (j * 256 + w * 64) * 16;
    }

    int am[2], bn[2];
    #pragma unroll
    for (int mi = 0; mi < 2; mi++) am[mi] = wm * 64 + mi * 32 + l32;
    #pragma unroll
    for (int ni = 0; ni < 2; ni++) bn[ni] = wn * 64 + ni * 32 + l32;

    v16f acc[2][2];
    #pragma unroll
    for (int mi = 0; mi < 2; mi++)
        #pragma unroll
        for (int ni = 0; ni < 2; ni++)
            #pragma unroll
            for (int r = 0; r < 16; r++) acc[mi][ni][r] = 0.f;

    int kt = K >> 5;
    #pragma unroll
    for (int j = 0; j < 2; j++) GLOAD16(gA[j], (char*)lA + offA[j]);
    #pragma unroll
    for (int j = 0; j < 2; j++) GLOAD16(gB[j], (char*)lB + offB[j]);
    #pragma unroll
    for (int j = 0; j < 2; j++) GLOAD16(gA[j] + 32, (char*)(lA + ABUF) + offA[j]);
    #pragma unroll
    for (int j = 0; j < 2; j++) GLOAD16(gB[j] + 32, (char*)(lB + BBUF) + offB[j]);

    int cur = 0;
    for (int it = 0; it < kt; it++) {
        int nx2 = cur + 2; if (nx2 >= 3) nx2 -= 3;
        __asm__ volatile("s_waitcnt vmcnt(4)" ::: "memory");
        __asm__ volatile("s_barrier" ::: "memory");
        {
            int kn = ((it + 2 < kt) ? it + 2 : kt - 1) << 5;
            #pragma unroll
            for (int j = 0; j < 2; j++) GLOAD16(gA[j] + kn, (char*)(lA + nx2 * ABUF) + offA[j]);
            #pragma unroll
            for (int j = 0; j < 2; j++) GLOAD16(gB[j] + kn, (char*)(lB + nx2 * BBUF) + offB[j]);
        }
        const unsigned short* bufA = lA + cur * ABUF;
        const unsigned short* bufB = lB + cur * BBUF;
        #pragma unroll
        for (int step = 0; step < 2; step++) {
            int gch = step * 2 + half;
            v8s af[2], bf[2];
            #pragma unroll
            for (int mi = 0; mi < 2; mi++)
                af[mi] = *(const v8s*)&bufA[am[mi] * 32 + ((gch ^ ((am[mi] >> 1) & 3)) * 8)];
            #pragma unroll
            for (int ni = 0; ni < 2; ni++)
                bf[ni] = *(const v8s*)&bufB[bn[ni] * 32 + ((gch ^ ((bn[ni] >> 1) & 3)) * 8)];
            #pragma unroll
            for (int mi = 0; mi < 2; mi++)
                #pragma unroll
                for (int ni = 0; ni < 2; ni++)
                    acc[mi][ni] = __builtin_amdgcn_mfma_f32_32x32x16_bf16(af[mi], bf[ni], acc[mi][ni], 0, 0, 0);
        }
        cur = cur + 1; if (cur >= 3) cur -= 3;
    }
    #pragma unroll
    for (int mi = 0; mi < 2; mi++) {
        #pragma unroll
        for (int ni = 0; ni < 2; ni++) {
            int col = n0 + wn * 64 + ni * 32 + l32;
            #pragma unroll
            for (int r = 0; r < 16; r++) {
                int row = m0 + wm * 64 + mi * 32 + (r & 3) + 8 * (r >> 2) + 4 * half;
                Cout[(size_t)row * N + col] = acc[mi][ni][r] + bias[col];
            }
        }
    }
}

// ---------------- V [b,t,h,d] (inside QKV) -> Vt [b,h,d,t] ----------------
__global__ void transpose_v(const unsigned short* __restrict__ QKV, unsigned short* __restrict__ Vt) {
    int t0 = blockIdx.x * 64;
    int bh = blockIdx.y;
    int b = bh >> 4, h = bh & 15;
    __shared__ unsigned short t[64][65];
    for (int i = threadIdx.x; i < 4096; i += 256) {
        int r = i >> 6, d = i & 63;
        t[d][r] = QKV[(size_t)(b * T_ + t0 + r) * QKVLD + h * 192 + 128 + d];
    }
    __syncthreads();
    for (int i = threadIdx.x; i < 4096; i += 256) {
        int d = i >> 6, r = i & 63;
        Vt[((size_t)bh * 64 + d) * T_ + t0 + r] = t[d][r];
    }
}

// ---------------- Flash attention v4 (unchanged) ----------------
__global__ __launch_bounds__(256) void attn_kernel(const unsigned short* __restrict__ QKV,
                                                   const unsigned short* __restrict__ Vt,
                                                   unsigned short* __restrict__ Ob) {
    int bh = blockIdx.x;                 // fast dim -> XCD = bh%8
    int qt = 7 - blockIdx.y;             // heavy-first
    int b = bh >> 4, h = bh & 15;
    int tid = threadIdx.x, lane = tid & 63, w = tid >> 6;
    int quad = lane >> 4, l16 = lane & 15;
    int qg0 = qt * 128 + w * 32;

    __shared__ unsigned short lK[2][2][64][32];  // [buf][d-half][s][32]  16 KB
    __shared__ unsigned short lV[2][64][32];     // [s-chunk][d][32]       8 KB
    __shared__ unsigned short lP[4][32][76];     // padded: conflict-free  19 KB

    v8s aq[2][2];
    #pragma unroll
    for (int st = 0; st < 2; st++) {
        const unsigned short* qp = QKV + (size_t)(b * T_ + qg0 + st * 16 + l16) * QKVLD + h * 192;
        aq[st][0] = *(const v8s*)(qp + quad * 8);
        aq[st][1] = *(const v8s*)(qp + 32 + quad * 8);
    }

    const unsigned short* gK[2];
    const unsigned short* gV[2];
    int ldsOff[2];
    #pragma unroll
    for (int j = 0; j < 2; j++) {
        int c = j * 256 + tid;
        int halfp = c >> 8, row = (c >> 2) & 63;
        int col8 = ((c & 3) ^ ((row >> 1) & 3)) * 8;
        gK[j] = QKV + (size_t)(b * T_ + row) * QKVLD + h * 192 + 64 + halfp * 32 + col8;
        gV[j] = Vt + ((size_t)bh * 64 + row) * T_ + halfp * 32 + col8;
        ldsOff[j] = (j * 256 + w * 64) * 16;
    }
    int rcol = (quad ^ ((l16 >> 1) & 3)) * 8;

    v4f accO[2][4];
    float lsum[2][4];
    #pragma unroll
    for (int st = 0; st < 2; st++)
        #pragma unroll
        for (int i = 0; i < 4; i++) { accO[st][i] = (v4f){0.f, 0.f, 0.f, 0.f}; lsum[st][i] = 0.f; }

    int ntiles = 2 * qt + 2;
    const float SC = 0.1803368801f;  // 0.125 * log2(e)

    #pragma unroll
    for (int j = 0; j < 2; j++)
        GLOAD16(gK[j], (char*)&lK[0][0][0][0] + ldsOff[j]);

    for (int it = 0; it < ntiles; it++) {
        int cur = it & 1, nxt = cur ^ 1;
        int s0 = it * 64;
        __asm__ volatile("s_waitcnt vmcnt(0)" ::: "memory");
        __asm__ volatile("s_barrier" ::: "memory");
        #pragma unroll
        for (int j = 0; j < 2; j++)
            GLOAD16(gV[j] + s0, (char*)&lV[0][0][0] + ldsOff[j]);
        __asm__ volatile("" ::: "memory");
        {
            int itn = (it + 1 < ntiles) ? it + 1 : it;
            size_t koff = (size_t)itn * 64 * QKVLD;
            #pragma unroll
            for (int j = 0; j < 2; j++)
                GLOAD16(gK[j] + koff, (char*)&lK[nxt][0][0][0] + ldsOff[j]);
        }
        bool act0 = (qg0 + 15 >= s0);
        bool act1 = (qg0 + 31 >= s0);
        if (act1) {
            v4f sf[2][4];
            #pragma unroll
            for (int nt = 0; nt < 4; nt++) {
                v8s bk0 = *(const v8s*)&lK[cur][0][nt * 16 + l16][rcol];
                v8s bk1 = *(const v8s*)&lK[cur][1][nt * 16 + l16][rcol];
                if (act0) {
                    v4f a = (v4f){0.f, 0.f, 0.f, 0.f};
                    a = __builtin_amdgcn_mfma_f32_16x16x32_bf16(aq[0][0], bk0, a, 0, 0, 0);
                    a = __builtin_amdgcn_mfma_f32_16x16x32_bf16(aq[0][1], bk1, a, 0, 0, 0);
                    sf[0][nt] = a;
                }
                v4f a1 = (v4f){0.f, 0.f, 0.f, 0.f};
                a1 = __builtin_amdgcn_mfma_f32_16x16x32_bf16(aq[1][0], bk0, a1, 0, 0, 0);
                a1 = __builtin_amdgcn_mfma_f32_16x16x32_bf16(aq[1][1], bk1, a1, 0, 0, 0);
                sf[1][nt] = a1;
            }
            bool diag = (it >= ntiles - 2);
            #pragma unroll
            for (int st = 0; st < 2; st++) {
                if (st == 0 && !act0) continue;
                if (diag) {
                    #pragma unroll
                    for (int nt = 0; nt < 4; nt++)
                        #pragma unroll
                        for (int r = 0; r < 4; r++) {
                            int sg = s0 + nt * 16 + l16;
                            int qg = qg0 + st * 16 + quad * 4 + r;
                            float p = (sg > qg) ? 0.f : fexp2(sf[st][nt][r] * SC);
                            lsum[st][r] += p;
                            lP[w][st * 16 + quad * 4 + r][nt * 16 + l16] = f2b(p);
                        }
                } else {
                    #pragma unroll
                    for (int nt = 0; nt < 4; nt++)
                        #pragma unroll
                        for (int r = 0; r < 4; r++) {
                            float p = fexp2(sf[st][nt][r] * SC);
                            lsum[st][r] += p;
                            lP[w][st * 16 + quad * 4 + r][nt * 16 + l16] = f2b(p);
                        }
                }
            }
        }
        __asm__ volatile("s_waitcnt vmcnt(2)" ::: "memory");
        __asm__ volatile("s_barrier" ::: "memory");
        __asm__ volatile("s_waitcnt lgkmcnt(0)" ::: "memory");
        if (act1) {
            #pragma unroll
            for (int sc = 0; sc < 2; sc++) {
                v8s ap0, ap1;
                if (act0) ap0 = *(const v8s*)&lP[w][l16][sc * 32 + quad * 8];
                ap1 = *(const v8s*)&lP[w][16 + l16][sc * 32 + quad * 8];
                #pragma unroll
                for (int dt = 0; dt < 4; dt++) {
                    v8s bv = *(const v8s*)&lV[sc][dt * 16 + l16][rcol];
                    if (act0) accO[0][dt] = __builtin_amdgcn_mfma_f32_16x16x32_bf16(ap0, bv, accO[0][dt], 0, 0, 0);
                    accO[1][dt] = __builtin_amdgcn_mfma_f32_16x16x32_bf16(ap1, bv, accO[1][dt], 0, 0, 0);
                }
            }
        }
    }
    #pragma unroll
    for (int st = 0; st < 2; st++)
        #pragma unroll
        for (int r = 0; r < 4; r++) {
            float s = lsum[st][r];
            #pragma unroll
            for (int off = 1; off < 16; off <<= 1) s += __shfl_xor(s, off, 64);
            float inv = 1.0f / s;
            int q = qg0 + st * 16 + quad * 4 + r;
            #pragma unroll
            for (int dt = 0; dt < 4; dt++) {
                int d = dt * 16 + l16;
                Ob[(size_t)(b * T_ + q) * (H_ * D_) + h * 64 + d] = f2b(accO[st][dt][r] * inv);
            }
        }
}

extern "C" void kernel_launch(void* const* d_in, const int* in_sizes, int n_in,
                              void* d_out, int out_size, void* d_ws, size_t ws_size,
                              hipStream_t stream) {
    const float* x     = (const float*)d_in[0];
    const float* Wq    = (const float*)d_in[1];
    const float* Wk    = (const float*)d_in[2];
    const float* Wv    = (const float*)d_in[3];
    const float* Wproj = (const float*)d_in[4];
    const float* bproj = (const float*)d_in[5];
    float* out = (float*)d_out;

    char* ws = (char*)d_ws;
    unsigned short* xb     = (unsigned short*)ws;                          // 16 MB  [8192][1024]
    unsigned short* WqkvT  = (unsigned short*)(ws + 16777216);             // 6 MB   [3072][1024]
    unsigned short* WprojT = (unsigned short*)(ws + 23068672);             // 2 MB   [1024][1024]
    unsigned short* QKV    = (unsigned short*)(ws + 25165824);             // 48 MB  [8192][3072]
    unsigned short* Vt     = (unsigned short*)(ws + 75497472);             // 16 MB  [B,H,D,T]
    unsigned short* Ob     = (unsigned short*)(ws + 92274688);             // 16 MB  [8192][1024]

    cast_x_kernel<<<dim3(8192), dim3(256), 0, stream>>>(x, xb, B_ * T_ * C_);
    transpose_wqkv<<<dim3(16, 48), dim3(256), 0, stream>>>(Wq, Wk, Wv, WqkvT);
    transpose_wproj<<<dim3(16, 16), dim3(256), 0, stream>>>(Wproj, WprojT);
    // QKV: R5-exact 2D grid (24 n-blocks x 32 m-blocks of 256)
    gemm_qkv<<<dim3(24, 32), dim3(256), 0, stream>>>(xb, WqkvT, QKV, 8192, 3072, 1024);
    transpose_v<<<dim3(16, 128), dim3(256), 0, stream>>>(QKV, Vt);
    attn_kernel<<<dim3(128, 8), dim3(256), 0, stream>>>(QKV, Vt, Ob);
    // proj: R6-exact 3-stage MB=2 with XCD stripe (512 blocks)
    gemm_proj<<<dim3(512), dim3(256), 0, stream>>>(Ob, WprojT, out, bproj, 8192, 1024, 1024);
}

// Round 9
// 240.657 us; speedup vs baseline: 1.1053x; 1.0050x over previous
//
#include <hip/hip_runtime.h>
#include <hip/hip_bf16.h>

#define B_ 8
#define T_ 1024
#define C_ 1024
#define H_ 16
#define D_ 64
#define QKVLD 3072  // H_*3*D_

typedef short v4s __attribute__((ext_vector_type(4)));
typedef short v8s __attribute__((ext_vector_type(8)));
typedef float v4f __attribute__((ext_vector_type(4)));
typedef float v16f __attribute__((ext_vector_type(16)));

__device__ __forceinline__ unsigned short f2b(float f) {
    unsigned int u = __builtin_bit_cast(unsigned int, f);
    unsigned int lsb = (u >> 16) & 1u;
    u += 0x7fffu + lsb;
    return (unsigned short)(u >> 16);
}

__device__ __forceinline__ float fexp2(float x) {
    return __expf(x * 0.69314718056f);   // compiler folds to v_exp_f32
}

// pack 4 fp32 -> 4 bf16 (round-half-up; inputs are P in [0,1], no NaN/neg)
__device__ __forceinline__ v4s pack4(float p0, float p1, float p2, float p3) {
    unsigned int a = (__builtin_bit_cast(unsigned int, p0) + 0x8000u) >> 16;
    unsigned int b = (__builtin_bit_cast(unsigned int, p1) + 0x8000u) & 0xFFFF0000u;
    unsigned int c = (__builtin_bit_cast(unsigned int, p2) + 0x8000u) >> 16;
    unsigned int d = (__builtin_bit_cast(unsigned int, p3) + 0x8000u) & 0xFFFF0000u;
    union { unsigned int u[2]; v4s v; } t;
    t.u[0] = a | b; t.u[1] = c | d;
    return t.v;
}

#define MFMA32(A, B, C) __builtin_amdgcn_mfma_f32_16x16x32_bf16(A, B, C, 0, 0, 0)
// v_mfma_f32_16x16x16_bf16 (gfx950-valid, cdna4_isa §10): clang name is the gfx90a-lineage
// "_1k" builtin. Used directly — __has_builtin is unreliable for aux-target builtins in the
// HIP host pass (R8 failure).
#define MFMA16(A, B, C) __builtin_amdgcn_mfma_f32_16x16x16bf16_1k(A, B, C, 0, 0, 0)

// async 16B global -> LDS. lds dest = wave-uniform base + lane*16.
#define GLOAD16(gp, lp)                                                          \
    __builtin_amdgcn_global_load_lds(                                            \
        (const __attribute__((address_space(1))) unsigned int*)(gp),             \
        (__attribute__((address_space(3))) unsigned int*)(lp), 16, 0, 0)

// ---------------- fused prep: cast x + transpose Wqkv + transpose Wproj ----------------
__global__ void prep_kernel(const float* __restrict__ x, const float* __restrict__ Wq,
                            const float* __restrict__ Wk, const float* __restrict__ Wv,
                            const float* __restrict__ Wproj,
                            unsigned short* __restrict__ xb,
                            unsigned short* __restrict__ WqkvT,
                            unsigned short* __restrict__ WprojT) {
    __shared__ unsigned short t[64][65];
    int g = blockIdx.x;
    if (g < 8192) {                       // cast x (fp32 -> bf16)
        int i = (g * 256 + (int)threadIdx.x) * 4;
        float4 v = *(const float4*)(x + i);
        ushort4 o;
        o.x = f2b(v.x); o.y = f2b(v.y); o.z = f2b(v.z); o.w = f2b(v.w);
        *(ushort4*)(xb + i) = o;
    } else if (g < 8192 + 768) {          // Wq/Wk/Wv [H][C][D] -> WqkvT [3072][1024]
        int idx = g - 8192;
        int z = idx >> 4;                 // h*3 + part
        int h = z / 3, part = z % 3;
        const float* src = (part == 0 ? Wq : (part == 1 ? Wk : Wv)) + (size_t)h * C_ * D_;
        int c0 = (idx & 15) * 64;
        for (int i = threadIdx.x; i < 4096; i += 256) {
            int r = i >> 6, d = i & 63;
            t[d][r] = f2b(src[(size_t)(c0 + r) * D_ + d]);
        }
        __syncthreads();
        unsigned short* dst = WqkvT + (size_t)(h * 192 + part * 64) * C_;
        for (int i = threadIdx.x; i < 4096; i += 256) {
            int d = i >> 6, r = i & 63;
            dst[(size_t)d * C_ + c0 + r] = t[d][r];
        }
    } else {                              // Wproj [1024][1024] -> WprojT (B^T)
        int idx = g - 8960;
        int n0 = (idx & 15) * 64, k0 = (idx >> 4) * 64;
        for (int i = threadIdx.x; i < 4096; i += 256) {
            int r = i >> 6, c = i & 63;
            t[c][r] = f2b(Wproj[(size_t)(k0 + r) * C_ + n0 + c]);
        }
        __syncthreads();
        for (int i = threadIdx.x; i < 4096; i += 256) {
            int n = i >> 6, k = i & 63;
            WprojT[(size_t)(n0 + n) * 1024 + k0 + k] = t[n][k];
        }
    }
}

// ---------------- GEMM v2s (R7-exact): 256x128 tile, 32x32x16 MFMA, 2-stage dbuf ----------
__global__ __launch_bounds__(256, 2) void gemm_qkv(const unsigned short* __restrict__ A,
                                                   const unsigned short* __restrict__ Bt,
                                                   unsigned short* __restrict__ Cout,
                                                   int M, int N, int K) {
    __shared__ unsigned short lA[2][256 * 32];   // 32 KB
    __shared__ unsigned short lB[2][128 * 32];   // 16 KB
    int tid = threadIdx.x;
    int m0 = blockIdx.y * 256, n0 = blockIdx.x * 128;
    int lane = tid & 63, w = tid >> 6;
    int half = lane >> 5, l32 = lane & 31;
    int wm = w >> 1, wn = w & 1;

    const unsigned short* gA[4];
    int offA[4];
    #pragma unroll
    for (int j = 0; j < 4; j++) {
        int c = j * 256 + tid;
        int row = c >> 2;
        int col8 = ((c & 3) ^ ((row >> 1) & 3)) * 8;
        gA[j] = A + (size_t)(m0 + row) * K + col8;
        offA[j] = (j * 256 + w * 64) * 16;
    }
    const unsigned short* gB[2];
    int offB[2];
    #pragma unroll
    for (int j = 0; j < 2; j++) {
        int c = j * 256 + tid;
        int row = c >> 2;
        int col8 = ((c & 3) ^ ((row >> 1) & 3)) * 8;
        gB[j] = Bt + (size_t)(n0 + row) * K + col8;
        offB[j] = (j * 256 + w * 64) * 16;
    }

    int am[4], bn[2];
    #pragma unroll
    for (int mi = 0; mi < 4; mi++) am[mi] = wm * 128 + mi * 32 + l32;
    #pragma unroll
    for (int ni = 0; ni < 2; ni++) bn[ni] = wn * 64 + ni * 32 + l32;

    v16f acc[4][2];
    #pragma unroll
    for (int mi = 0; mi < 4; mi++)
        #pragma unroll
        for (int ni = 0; ni < 2; ni++)
            #pragma unroll
            for (int r = 0; r < 16; r++) acc[mi][ni][r] = 0.f;

    int ktiles = K >> 5;
    #pragma unroll
    for (int j = 0; j < 4; j++) GLOAD16(gA[j], (char*)&lA[0][0] + offA[j]);
    #pragma unroll
    for (int j = 0; j < 2; j++) GLOAD16(gB[j], (char*)&lB[0][0] + offB[j]);

    for (int it = 0; it < ktiles; it++) {
        int cur = it & 1, nxt = cur ^ 1;
        __asm__ volatile("s_waitcnt vmcnt(0)" ::: "memory");
        __asm__ volatile("s_barrier" ::: "memory");
        {
            int kn = (it + 1 < ktiles) ? (it + 1) * 32 : it * 32;
            #pragma unroll
            for (int j = 0; j < 4; j++) GLOAD16(gA[j] + kn, (char*)&lA[nxt][0] + offA[j]);
            #pragma unroll
            for (int j = 0; j < 2; j++) GLOAD16(gB[j] + kn, (char*)&lB[nxt][0] + offB[j]);
        }
        #pragma unroll
        for (int step = 0; step < 2; step++) {
            int g = step * 2 + half;
            v8s af[4], bf[2];
            #pragma unroll
            for (int mi = 0; mi < 4; mi++)
                af[mi] = *(const v8s*)&lA[cur][am[mi] * 32 + ((g ^ ((am[mi] >> 1) & 3)) * 8)];
            #pragma unroll
            for (int ni = 0; ni < 2; ni++)
                bf[ni] = *(const v8s*)&lB[cur][bn[ni] * 32 + ((g ^ ((bn[ni] >> 1) & 3)) * 8)];
            #pragma unroll
            for (int mi = 0; mi < 4; mi++)
                #pragma unroll
                for (int ni = 0; ni < 2; ni++)
                    acc[mi][ni] = __builtin_amdgcn_mfma_f32_32x32x16_bf16(af[mi], bf[ni], acc[mi][ni], 0, 0, 0);
        }
    }
    #pragma unroll
    for (int mi = 0; mi < 4; mi++) {
        #pragma unroll
        for (int ni = 0; ni < 2; ni++) {
            int col = n0 + wn * 64 + ni * 32 + l32;
            #pragma unroll
            for (int r = 0; r < 16; r++) {
                int row = m0 + wm * 128 + mi * 32 + (r & 3) + 8 * (r >> 2) + 4 * half;
                Cout[(size_t)row * N + col] = f2b(acc[mi][ni][r]);
            }
        }
    }
}

// ---------------- GEMM proj (R7-exact): 128x128, 3-stage pipeline, XCD stripe ------
__global__ __launch_bounds__(256, 3) void gemm_proj(const unsigned short* __restrict__ A,
                                                    const unsigned short* __restrict__ Bt,
                                                    float* __restrict__ Cout,
                                                    const float* __restrict__ bias,
                                                    int M, int N, int K) {
    constexpr int ABUF = 128 * 32;
    constexpr int BBUF = 128 * 32;
    __shared__ unsigned short lA[3 * ABUF];
    __shared__ unsigned short lB[3 * BBUF];

    int tid = threadIdx.x;
    int lane = tid & 63, w = tid >> 6;
    int half = lane >> 5, l32 = lane & 31;
    int wm = w >> 1, wn = w & 1;

    int g = blockIdx.x;
    int nbm = M / 128;
    int stripe = nbm >> 3;
    int xcd = g & 7, s = g >> 3;
    int m0 = (xcd * stripe + (s % stripe)) * 128;
    int n0 = (s / stripe) * 128;

    const unsigned short* gA[2];
    int offA[2];
    #pragma unroll
    for (int j = 0; j < 2; j++) {
        int c = j * 256 + tid;
        int row = c >> 2;
        int col8 = ((c & 3) ^ ((row >> 1) & 3)) * 8;
        gA[j] = A + (size_t)(m0 + row) * K + col8;
        offA[j] = (j * 256 + w * 64) * 16;
    }
    const unsigned short* gB[2];
    int offB[2];
    #pragma unroll
    for (int j = 0; j < 2; j++) {
        int c = j * 256 + tid;
        int row = c >> 2;
        int col8 = ((c & 3) ^ ((row >> 1) & 3)) * 8;
        gB[j] = Bt + (size_t)(n0 + row) * K + col8;
        offB[j] = (j * 256 + w * 64) * 16;
    }

    int am[2], bn[2];
    #pragma unroll
    for (int mi = 0; mi < 2; mi++) am[mi] = wm * 64 + mi * 32 + l32;
    #pragma unroll
    for (int ni = 0; ni < 2; ni++) bn[ni] = wn * 64 + ni * 32 + l32;

    v16f acc[2][2];
    #pragma unroll
    for (int mi = 0; mi < 2; mi++)
        #pragma unroll
        for (int ni = 0; ni < 2; ni++)
            #pragma unroll
            for (int r = 0; r < 16; r++) acc[mi][ni][r] = 0.f;

    int kt = K >> 5;
    #pragma unroll
    for (int j = 0; j < 2; j++) GLOAD16(gA[j], (char*)lA + offA[j]);
    #pragma unroll
    for (int j = 0; j < 2; j++) GLOAD16(gB[j], (char*)lB + offB[j]);
    #pragma unroll
    for (int j = 0; j < 2; j++) GLOAD16(gA[j] + 32, (char*)(lA + ABUF) + offA[j]);
    #pragma unroll
    for (int j = 0; j < 2; j++) GLOAD16(gB[j] + 32, (char*)(lB + BBUF) + offB[j]);

    int cur = 0;
    for (int it = 0; it < kt; it++) {
        int nx2 = cur + 2; if (nx2 >= 3) nx2 -= 3;
        __asm__ volatile("s_waitcnt vmcnt(4)" ::: "memory");
        __asm__ volatile("s_barrier" ::: "memory");
        {
            int kn = ((it + 2 < kt) ? it + 2 : kt - 1) << 5;
            #pragma unroll
            for (int j = 0; j < 2; j++) GLOAD16(gA[j] + kn, (char*)(lA + nx2 * ABUF) + offA[j]);
            #pragma unroll
            for (int j = 0; j < 2; j++) GLOAD16(gB[j] + kn, (char*)(lB + nx2 * BBUF) + offB[j]);
        }
        const unsigned short* bufA = lA + cur * ABUF;
        const unsigned short* bufB = lB + cur * BBUF;
        #pragma unroll
        for (int step = 0; step < 2; step++) {
            int gch = step * 2 + half;
            v8s af[2], bf[2];
            #pragma unroll
            for (int mi = 0; mi < 2; mi++)
                af[mi] = *(const v8s*)&bufA[am[mi] * 32 + ((gch ^ ((am[mi] >> 1) & 3)) * 8)];
            #pragma unroll
            for (int ni = 0; ni < 2; ni++)
                bf[ni] = *(const v8s*)&bufB[bn[ni] * 32 + ((gch ^ ((bn[ni] >> 1) & 3)) * 8)];
            #pragma unroll
            for (int mi = 0; mi < 2; mi++)
                #pragma unroll
                for (int ni = 0; ni < 2; ni++)
                    acc[mi][ni] = __builtin_amdgcn_mfma_f32_32x32x16_bf16(af[mi], bf[ni], acc[mi][ni], 0, 0, 0);
        }
        cur = cur + 1; if (cur >= 3) cur -= 3;
    }
    #pragma unroll
    for (int mi = 0; mi < 2; mi++) {
        #pragma unroll
        for (int ni = 0; ni < 2; ni++) {
            int col = n0 + wn * 64 + ni * 32 + l32;
            #pragma unroll
            for (int r = 0; r < 16; r++) {
                int row = m0 + wm * 64 + mi * 32 + (r & 3) + 8 * (r >> 2) + 4 * half;
                Cout[(size_t)row * N + col] = acc[mi][ni][r] + bias[col];
            }
        }
    }
}

// ---------------- V [b,t,h,d] (inside QKV) -> Vt [b,h,d,t] ----------------
__global__ void transpose_v(const unsigned short* __restrict__ QKV, unsigned short* __restrict__ Vt) {
    int t0 = blockIdx.x * 64;
    int bh = blockIdx.y;
    int b = bh >> 4, h = bh & 15;
    __shared__ unsigned short t[64][65];
    for (int i = threadIdx.x; i < 4096; i += 256) {
        int r = i >> 6, d = i & 63;
        t[d][r] = QKV[(size_t)(b * T_ + t0 + r) * QKVLD + h * 192 + 128 + d];
    }
    __syncthreads();
    for (int i = threadIdx.x; i < 4096; i += 256) {
        int d = i >> 6, r = i & 63;
        Vt[((size_t)bh * 64 + d) * T_ + t0 + r] = t[d][r];
    }
}

// ---------------- Flash attention v5: S-transposed, register-resident P ----------------
// QK computed as S^T = K·Q^T (A=K frags, B=Q frags): C-layout gives lane = S^T[s=quad*4+r][q=l16],
// which IS the A-fragment layout of mfma_f32_16x16x16_bf16 (k=quad*4+j) -> P feeds PV directly
// from registers. No lP LDS, no ds_write/ds_read of P, no lgkm wait. LDS = 24 KB.
__global__ __launch_bounds__(256) void attn_kernel(const unsigned short* __restrict__ QKV,
                                                   const unsigned short* __restrict__ Vt,
                                                   unsigned short* __restrict__ Ob) {
    int bh = blockIdx.x;                 // fast dim -> XCD = bh%8
    int qt = 7 - blockIdx.y;             // heavy-first
    int b = bh >> 4, h = bh & 15;
    int tid = threadIdx.x, lane = tid & 63, w = tid >> 6;
    int quad = lane >> 4, l16 = lane & 15;
    int qg0 = qt * 128 + w * 32;

    __shared__ unsigned short lK[2][2][64][32];  // [buf][d-half][s][32]  16 KB
    __shared__ unsigned short lV[2][64][32];     // [s-chunk][d][32]       8 KB

    // Q fragments (used as MFMA-B operand: B[n=q=l16][k=d=quad*8+j])
    v8s aq[2][2];
    #pragma unroll
    for (int st = 0; st < 2; st++) {
        const unsigned short* qp = QKV + (size_t)(b * T_ + qg0 + st * 16 + l16) * QKVLD + h * 192;
        aq[st][0] = *(const v8s*)(qp + quad * 8);
        aq[st][1] = *(const v8s*)(qp + 32 + quad * 8);
    }

    const unsigned short* gK[2];
    const unsigned short* gV[2];
    int ldsOff[2];
    #pragma unroll
    for (int j = 0; j < 2; j++) {
        int c = j * 256 + tid;
        int halfp = c >> 8, row = (c >> 2) & 63;
        int col8 = ((c & 3) ^ ((row >> 1) & 3)) * 8;
        gK[j] = QKV + (size_t)(b * T_ + row) * QKVLD + h * 192 + 64 + halfp * 32 + col8;
        gV[j] = Vt + ((size_t)bh * 64 + row) * T_ + halfp * 32 + col8;
        ldsOff[j] = (j * 256 + w * 64) * 16;
    }
    int rcol = (quad ^ ((l16 >> 1) & 3)) * 8;    // un-swizzled K read column

    v4f accO[2][4];
    float lsum[2] = {0.f, 0.f};                  // per-lane: q = qg0 + st*16 + l16
    #pragma unroll
    for (int st = 0; st < 2; st++)
        #pragma unroll
        for (int i = 0; i < 4; i++) accO[st][i] = (v4f){0.f, 0.f, 0.f, 0.f};

    int ntiles = 2 * qt + 2;
    const float SC = 0.1803368801f;  // 0.125 * log2(e)

    #pragma unroll
    for (int j = 0; j < 2; j++)
        GLOAD16(gK[j], (char*)&lK[0][0][0][0] + ldsOff[j]);

    for (int it = 0; it < ntiles; it++) {
        int cur = it & 1, nxt = cur ^ 1;
        int s0 = it * 64;
        __asm__ volatile("s_waitcnt vmcnt(0)" ::: "memory");
        __asm__ volatile("s_barrier" ::: "memory");
        #pragma unroll
        for (int j = 0; j < 2; j++)
            GLOAD16(gV[j] + s0, (char*)&lV[0][0][0] + ldsOff[j]);
        __asm__ volatile("" ::: "memory");
        {
            int itn = (it + 1 < ntiles) ? it + 1 : it;
            size_t koff = (size_t)itn * 64 * QKVLD;
            #pragma unroll
            for (int j = 0; j < 2; j++)
                GLOAD16(gK[j] + koff, (char*)&lK[nxt][0][0][0] + ldsOff[j]);
        }
        bool act0 = (qg0 + 15 >= s0);        // strip 0 (lower q) active
        bool act1 = (qg0 + 31 >= s0);        // strip 1
        v4s pP[2][4];
        if (act1) {
            // S^T = K·Q^T ; then exp2 -> pack to A-frags
            v4f sf[2][4];
            #pragma unroll
            for (int nt = 0; nt < 4; nt++) {
                v8s bk0 = *(const v8s*)&lK[cur][0][nt * 16 + l16][rcol];
                v8s bk1 = *(const v8s*)&lK[cur][1][nt * 16 + l16][rcol];
                v4f a1 = (v4f){0.f, 0.f, 0.f, 0.f};
                a1 = MFMA32(bk0, aq[1][0], a1);
                a1 = MFMA32(bk1, aq[1][1], a1);
                sf[1][nt] = a1;
                if (act0) {
                    v4f a0 = (v4f){0.f, 0.f, 0.f, 0.f};
                    a0 = MFMA32(bk0, aq[0][0], a0);
                    a0 = MFMA32(bk1, aq[0][1], a0);
                    sf[0][nt] = a0;
                }
            }
            bool diag = (it >= ntiles - 2);
            #pragma unroll
            for (int st = 0; st < 2; st++) {
                if (st == 0 && !act0) continue;
                int qg = qg0 + st * 16 + l16;
                #pragma unroll
                for (int nt = 0; nt < 4; nt++) {
                    float p[4];
                    #pragma unroll
                    for (int r = 0; r < 4; r++) {
                        if (diag) {
                            int sg = s0 + nt * 16 + quad * 4 + r;
                            p[r] = (sg > qg) ? 0.f : fexp2(sf[st][nt][r] * SC);
                        } else {
                            p[r] = fexp2(sf[st][nt][r] * SC);
                        }
                        lsum[st] += p[r];
                    }
                    pP[st][nt] = pack4(p[0], p[1], p[2], p[3]);
                }
            }
        }
        __asm__ volatile("s_waitcnt vmcnt(2)" ::: "memory");
        __asm__ volatile("s_barrier" ::: "memory");
        // O += P V : P from registers (A-frag), V^T from LDS (B-frag, b64, swizzled)
        if (act1) {
            #pragma unroll
            for (int kb = 0; kb < 4; kb++) {
                int sc_ = kb >> 1;
                int ccg = (kb & 1) * 2 + (quad >> 1);
                #pragma unroll
                for (int dt = 0; dt < 4; dt++) {
                    int d = dt * 16 + l16;
                    int ccp = ccg ^ ((l16 >> 1) & 3);
                    v4s bv = *(const v4s*)&lV[sc_][d][ccp * 8 + (quad & 1) * 4];
                    accO[1][dt] = MFMA16(pP[1][kb], bv, accO[1][dt]);
                    if (act0) accO[0][dt] = MFMA16(pP[0][kb], bv, accO[0][dt]);
                }
            }
        }
    }
    // epilogue: reduce lsum across quads (2 shuffles), redistribute by q, divide, store
    #pragma unroll
    for (int st = 0; st < 2; st++) {
        float ls = lsum[st];
        ls += __shfl_xor(ls, 16, 64);
        ls += __shfl_xor(ls, 32, 64);     // now every lane holds total for q = ..+l16
        #pragma unroll
        for (int r = 0; r < 4; r++) {
            float lq = __shfl(ls, quad * 4 + r, 64);   // lsum for q_local = quad*4+r
            float inv = 1.0f / lq;
            int q = qg0 + st * 16 + quad * 4 + r;
            #pragma unroll
            for (int dt = 0; dt < 4; dt++) {
                int d = dt * 16 + l16;
                Ob[(size_t)(b * T_ + q) * (H_ * D_) + h * 64 + d] = f2b(accO[st][dt][r] * inv);
            }
        }
    }
}

extern "C" void kernel_launch(void* const* d_in, const int* in_sizes, int n_in,
                              void* d_out, int out_size, void* d_ws, size_t ws_size,
                              hipStream_t stream) {
    const float* x     = (const float*)d_in[0];
    const float* Wq    = (const float*)d_in[1];
    const float* Wk    = (const float*)d_in[2];
    const float* Wv    = (const float*)d_in[3];
    const float* Wproj = (const float*)d_in[4];
    const float* bproj = (const float*)d_in[5];
    float* out = (float*)d_out;

    char* ws = (char*)d_ws;
    unsigned short* xb     = (unsigned short*)ws;                          // 16 MB  [8192][1024]
    unsigned short* WqkvT  = (unsigned short*)(ws + 16777216);             // 6 MB   [3072][1024]
    unsigned short* WprojT = (unsigned short*)(ws + 23068672);             // 2 MB   [1024][1024]
    unsigned short* QKV    = (unsigned short*)(ws + 25165824);             // 48 MB  [8192][3072]
    unsigned short* Vt     = (unsigned short*)(ws + 75497472);             // 16 MB  [B,H,D,T]
    unsigned short* Ob     = (unsigned short*)(ws + 92274688);             // 16 MB  [8192][1024]

    prep_kernel<<<dim3(9216), dim3(256), 0, stream>>>(x, Wq, Wk, Wv, Wproj, xb, WqkvT, WprojT);
    gemm_qkv<<<dim3(24, 32), dim3(256), 0, stream>>>(xb, WqkvT, QKV, 8192, 3072, 1024);
    transpose_v<<<dim3(16, 128), dim3(256), 0, stream>>>(QKV, Vt);
    attn_kernel<<<dim3(128, 8), dim3(256), 0, stream>>>(QKV, Vt, Ob);
    gemm_proj<<<dim3(512), dim3(256), 0, stream>>>(Ob, WprojT, out, bproj, 8192, 1024, 1024);
}